// Round 9
// baseline (927.554 us; speedup 1.0000x reference)
//
#include <hip/hip_runtime.h>
#include <math.h>

#define BMAX 4
#define CAP 16384
typedef __attribute__((ext_vector_type(8))) short s16x8;
typedef __attribute__((ext_vector_type(4))) float f32x4;

__device__ __forceinline__ float sigmoidf_(float x) { return 1.f / (1.f + expf(-x)); }

// f32 -> bf16 RNE
__device__ __forceinline__ ushort f2b(float f) {
    uint u = __float_as_uint(f);
    u = u + 0x7FFFu + ((u >> 16) & 1u);
    return (ushort)(u >> 16);
}
__device__ __forceinline__ uint pk2(float a, float b) {
    return (uint)f2b(a) | ((uint)f2b(b) << 16);
}

// ---------------- rulebook build: per-tap (in,out) pair lists (center tap 13 excluded)
__global__ __launch_bounds__(256)
void k_rule(const int* __restrict__ nbr, int2* __restrict__ pairs,
            int* __restrict__ gcnt, int N)
{
    __shared__ int l[64 * 27];
    int tid = threadIdx.x;
    int n0 = blockIdx.x * 64;
    int nrows = min(64, N - n0);
    int tot = nrows * 27;
    for (int t = tid; t < tot; t += 256) l[t] = nbr[(size_t)n0 * 27 + t];
    __syncthreads();
    int w = tid >> 6, lane = tid & 63;
    int k0 = w * 7, k1 = min(27, k0 + 7);
    for (int k = k0; k < k1; ++k) {
        if (k == 13) continue;
        int j = (lane < nrows) ? l[lane * 27 + k] : -1;
        bool valid = j >= 0;
        unsigned long long mask = __ballot(valid);
        int cnt = (int)__popcll(mask);
        int base = 0;
        if (lane == 0 && cnt) base = atomicAdd(&gcnt[k], cnt);
        base = __shfl(base, 0, 64);
        if (valid) {
            int idx = base + (int)__popcll(mask & ((1ull << lane) - 1ull));
            if (idx < CAP) pairs[(size_t)k * CAP + idx] = make_int2(j, n0 + lane);
        }
    }
}

// ---------------- fusion gate: s[n] = sigmoid(feat_mos[n].w+b); per-block batch counts
__global__ __launch_bounds__(256)
void k_fuse_s(const float* __restrict__ mos, const float* __restrict__ spw,
              const float* __restrict__ spb, const int* __restrict__ bids,
              float* __restrict__ s_out, float* __restrict__ pc, int N)
{
    __shared__ float lcnt[BMAX];
    int tid = threadIdx.x;
    if (tid < BMAX) lcnt[tid] = 0.f;
    __syncthreads();
    int n = blockIdx.x * 256 + tid;
    if (n < N) {
        const float* mr = mos + (size_t)n * 64;
        float dot = 0.f;
        #pragma unroll
        for (int c = 0; c < 64; c += 4) {
            float4 m4 = *(const float4*)(mr + c);
            float4 w4 = *(const float4*)(spw + c);
            dot += m4.x * w4.x + m4.y * w4.y + m4.z * w4.z + m4.w * w4.w;
        }
        float s = sigmoidf_(dot + spb[0]);
        s_out[n] = s;
        atomicAdd(&lcnt[bids[n]], 1.f);
    }
    __syncthreads();
    if (tid < BMAX) pc[(size_t)blockIdx.x * 4 + tid] = lcnt[tid];
}

// ---------------- stage 1: per-block partial seg-sums of fm = s[n]*feat_sem[n,c]
__global__ __launch_bounds__(256)
void k_seg_part(const float* __restrict__ fsem, const float* __restrict__ s_buf,
                const int* __restrict__ bids, float* __restrict__ part, int N)
{
    __shared__ float lseg[BMAX * 64];
    int tid = threadIdx.x;
    lseg[tid] = 0.f;
    __syncthreads();
    int c = tid & 63;
    int slot = blockIdx.x * 4 + (tid >> 6);
    int nslots = gridDim.x * 4;
    int chunk = (N + nslots - 1) / nslots;
    int n0 = slot * chunk;
    int n1 = min(N, n0 + chunk);
    float acc = 0.f; int curb = -1;
    int n = n0;
    for (; n + 4 <= n1; n += 4) {
        int b0 = bids[n], b3 = bids[n + 3];
        float s0 = s_buf[n], s1 = s_buf[n + 1], s2 = s_buf[n + 2], s3 = s_buf[n + 3];
        float f0 = fsem[(size_t)n * 64 + c];
        float f1 = fsem[(size_t)(n + 1) * 64 + c];
        float f2 = fsem[(size_t)(n + 2) * 64 + c];
        float f3 = fsem[(size_t)(n + 3) * 64 + c];
        if (b0 == b3) {
            if (b0 != curb) {
                if (curb >= 0) atomicAdd(&lseg[curb * 64 + c], acc);
                acc = 0.f; curb = b0;
            }
            acc += s0 * f0 + s1 * f1 + s2 * f2 + s3 * f3;
        } else {
            int bb[4] = { b0, bids[n + 1], bids[n + 2], b3 };
            float sv[4] = { s0, s1, s2, s3 };
            float fv[4] = { f0, f1, f2, f3 };
            #pragma unroll
            for (int q = 0; q < 4; ++q) {
                if (bb[q] != curb) {
                    if (curb >= 0) atomicAdd(&lseg[curb * 64 + c], acc);
                    acc = 0.f; curb = bb[q];
                }
                acc += sv[q] * fv[q];
            }
        }
    }
    for (; n < n1; ++n) {
        int b = bids[n];
        if (b != curb) {
            if (curb >= 0) atomicAdd(&lseg[curb * 64 + c], acc);
            acc = 0.f; curb = b;
        }
        acc += s_buf[n] * fsem[(size_t)n * 64 + c];
    }
    if (curb >= 0) atomicAdd(&lseg[curb * 64 + c], acc);
    __syncthreads();
    part[(size_t)blockIdx.x * 256 + tid] = lseg[tid];
}

// ---------------- stage 2: reduce partials -> seg[256]
__global__ __launch_bounds__(1024)
void k_seg_red(const float* __restrict__ part, float* __restrict__ seg, int nblk)
{
    __shared__ float l[1024];
    int tid = threadIdx.x;
    int col = tid & 255, grp = tid >> 8;
    float a = 0.f;
    #pragma unroll 8
    for (int j = grp; j < nblk; j += 4) a += part[(size_t)j * 256 + col];
    l[tid] = a;
    __syncthreads();
    if (tid < 256) seg[tid] = l[tid] + l[256 + tid] + l[512 + tid] + l[768 + tid];
}

// ---------------- vec = softmax(seg_mean @ fus_ch_w + b)*64; also reduces counts
__global__ void k_vec(const float* __restrict__ seg, const float* __restrict__ pc, int nbc,
                      const float* __restrict__ chw, const float* __restrict__ chb,
                      float* __restrict__ vec, float* __restrict__ cnt_out)
{
    __shared__ float lred[256];
    __shared__ float lcnt[4];
    int tid = threadIdx.x;
    float a = 0.f;
    for (int j = tid >> 2; j < nbc; j += 64) a += pc[(size_t)j * 4 + (tid & 3)];
    lred[tid] = a;
    __syncthreads();
    if (tid < 4) {
        float s = 0.f;
        #pragma unroll 8
        for (int j = 0; j < 64; ++j) s += lred[j * 4 + tid];
        lcnt[tid] = s;
        cnt_out[tid] = s;
    }
    __syncthreads();
    int b = tid >> 6;
    int c = tid & 63;
    float mean = seg[b * 64 + c] / lcnt[b];
    float v = chb[c];
    #pragma unroll 1
    for (int i = 0; i < 64; ++i) {
        float mi = __shfl(mean, i, 64);
        v += mi * chw[i * 64 + c];
    }
    float m = v;
    #pragma unroll
    for (int off = 32; off; off >>= 1) m = fmaxf(m, __shfl_xor(m, off, 64));
    float e = expf(v - m);
    float ssum = e;
    #pragma unroll
    for (int off = 32; off; off >>= 1) ssum += __shfl_xor(ssum, off, 64);
    vec[b * 64 + c] = e / ssum * 64.f;
}

// ---------------- gated input -> bf16 (8 thr/voxel)
__global__ __launch_bounds__(256)
void k_gate_cvt(const float* __restrict__ fs, const float* __restrict__ s_buf,
                const float* __restrict__ vec, const int* __restrict__ bids,
                ushort* __restrict__ out, int N)
{
    int gid = blockIdx.x * 256 + threadIdx.x;
    int n = gid >> 3;
    if (n >= N) return;
    int c0 = (gid & 7) * 8;
    float s = s_buf[n];
    const float* vr = vec + bids[n] * 64 + c0;
    const float* fr = fs + (size_t)n * 64 + c0;
    float4 f0 = *(const float4*)fr, f1 = *(const float4*)(fr + 4);
    float4 v0 = *(const float4*)vr, v1 = *(const float4*)(vr + 4);
    float g0 = f0.x * (1.f + s * v0.x), g1 = f0.y * (1.f + s * v0.y);
    float g2 = f0.z * (1.f + s * v0.z), g3 = f0.w * (1.f + s * v0.w);
    float g4 = f1.x * (1.f + s * v1.x), g5 = f1.y * (1.f + s * v1.y);
    float g6 = f1.z * (1.f + s * v1.z), g7 = f1.w * (1.f + s * v1.w);
    uint4 o; o.x = pk2(g0, g1); o.y = pk2(g2, g3); o.z = pk2(g4, g5); o.w = pk2(g6, g7);
    *(uint4*)(out + (size_t)n * 64 + c0) = o;
}

// ---------------- pack one weight element into MFMA B-fragment layout
__device__ __forceinline__ void wpack_one(const float* __restrict__ W, int CIN,
                                          int tt, ushort* __restrict__ dst)
{
    int nkc = CIN >> 5;
    int lane = tt & 63;
    int nt = (tt >> 6) & 1;
    int kc = (tt >> 7) % nkc;
    int k = tt / (nkc * 128);
    int kk = kc * 32 + (lane >> 4) * 8;
    int col = nt * 16 + (lane & 15);
    const float* src = W + ((size_t)k * CIN + kk) * 32 + col;
    float v[8];
    #pragma unroll
    for (int e = 0; e < 8; ++e) v[e] = src[e * 32];
    uint4 o; o.x = pk2(v[0], v[1]); o.y = pk2(v[2], v[3]);
    o.z = pk2(v[4], v[5]); o.w = pk2(v[6], v[7]);
    *(uint4*)(dst + (size_t)tt * 8) = o;
}

__global__ __launch_bounds__(256)
void k_wpack_all(const float* __restrict__ W0, const float* __restrict__ W1,
                 const float* __restrict__ W2, const float* __restrict__ W3,
                 const float* __restrict__ W4, ushort* __restrict__ P)
{
    int t = blockIdx.x * 256 + threadIdx.x;
    if (t < 6912) {
        wpack_one(W0, 64, t, P);
    } else {
        int r = t - 6912;
        int s = r / 3456;
        int tt = r % 3456;
        if (s >= 4) return;
        const float* W = (s == 0) ? W1 : (s == 1) ? W2 : (s == 2) ? W3 : W4;
        wpack_one(W, 32, tt, P + 55296 + s * 27648);
    }
}

// ---------------- center-tap dense conv: wave = 16 voxels, coalesced own-row reads
template<int CIN, bool BIAS>
__global__ __launch_bounds__(256)
void k_center(const ushort* __restrict__ inb, const ushort* __restrict__ wpk13,
              const float* __restrict__ bias, float* __restrict__ outf, int N)
{
    constexpr int NKC = CIN / 32;
    int tid = threadIdx.x;
    int lane = tid & 63;
    int gw = (blockIdx.x * 256 + tid) >> 6;
    int vbase = gw * 16;
    if (vbase >= N) return;
    int row = lane & 15;
    int koff = (lane >> 4) * 8;
    int vr = min(vbase + row, N - 1);
    f32x4 acc0 = {0.f,0.f,0.f,0.f}, acc1 = {0.f,0.f,0.f,0.f};
    #pragma unroll
    for (int kc = 0; kc < NKC; ++kc) {
        s16x8 a = *(const s16x8*)(inb + (size_t)vr * CIN + kc * 32 + koff);
        const ushort* wb = wpk13 + (size_t)kc * 1024 + lane * 8;
        s16x8 b0 = *(const s16x8*)(wb);
        s16x8 b1 = *(const s16x8*)(wb + 512);
        acc0 = __builtin_amdgcn_mfma_f32_16x16x32_bf16(a, b0, acc0, 0, 0, 0);
        acc1 = __builtin_amdgcn_mfma_f32_16x16x32_bf16(a, b1, acc1, 0, 0, 0);
    }
    int ccol = lane & 15;
    int crow = (lane >> 4) * 4;
    float b0v = BIAS ? bias[ccol] : 0.f;
    float b1v = BIAS ? bias[16 + ccol] : 0.f;
    #pragma unroll
    for (int i = 0; i < 4; ++i) {
        int v = vbase + crow + i;
        if (v < N) {
            outf[(size_t)v * 32 + ccol] = acc0[i] + b0v;
            outf[(size_t)v * 32 + 16 + ccol] = acc1[i] + b1v;
        }
    }
}

// ---------------- sparse scatter conv: wave = 16 valid pairs of one tap; atomic f32 out
template<int CIN>
__global__ __launch_bounds__(256)
void k_scatter(const ushort* __restrict__ inb, const int2* __restrict__ pairs,
               const int* __restrict__ gcnt, const ushort* __restrict__ wpk,
               float* __restrict__ outf, int N)
{
    constexpr int NKC = CIN / 32;
    int tid = threadIdx.x;
    int lane = tid & 63;
    int gw = blockIdx.x * 4 + (tid >> 6);
    int k = gw >> 10;               // 1024 tiles per tap
    int tile = gw & 1023;
    int cnt = min(gcnt[k], CAP);
    int p0 = tile * 16;
    if (p0 >= cnt) return;
    int row = lane & 15;
    int koff = (lane >> 4) * 8;
    int pidx = min(p0 + row, cnt - 1);
    int2 pr = pairs[(size_t)k * CAP + pidx];
    f32x4 acc0 = {0.f,0.f,0.f,0.f}, acc1 = {0.f,0.f,0.f,0.f};
    #pragma unroll
    for (int kc = 0; kc < NKC; ++kc) {
        s16x8 a = *(const s16x8*)(inb + (size_t)pr.x * CIN + kc * 32 + koff);
        const ushort* wb = wpk + (size_t)(k * NKC + kc) * 1024 + lane * 8;
        s16x8 b0 = *(const s16x8*)(wb);
        s16x8 b1 = *(const s16x8*)(wb + 512);
        acc0 = __builtin_amdgcn_mfma_f32_16x16x32_bf16(a, b0, acc0, 0, 0, 0);
        acc1 = __builtin_amdgcn_mfma_f32_16x16x32_bf16(a, b1, acc1, 0, 0, 0);
    }
    int ccol = lane & 15;
    int crow = (lane >> 4) * 4;
    #pragma unroll
    for (int i = 0; i < 4; ++i) {
        int pi = p0 + crow + i;
        if (pi < cnt) {
            int outn = pairs[(size_t)k * CAP + pi].y;
            atomicAdd(&outf[(size_t)outn * 32 + ccol], acc0[i]);
            atomicAdd(&outf[(size_t)outn * 32 + 16 + ccol], acc1[i]);
        }
    }
}

// ---------------- per-block channel sum/sq partials of a finished f32 tensor
__global__ __launch_bounds__(256)
void k_statsp(const float* __restrict__ t, float* __restrict__ part, int N)
{
    __shared__ float lsum[32];
    __shared__ float lsq[32];
    int tid = threadIdx.x;
    if (tid < 32) { lsum[tid] = 0.f; lsq[tid] = 0.f; }
    __syncthreads();
    int gid = blockIdx.x * 256 + tid;
    int n = gid >> 2;
    int c0 = (gid & 3) * 8;
    if (n < N) {
        const float* tr = t + (size_t)n * 32 + c0;
        float4 t0 = *(const float4*)tr, t1 = *(const float4*)(tr + 4);
        float v[8] = { t0.x, t0.y, t0.z, t0.w, t1.x, t1.y, t1.z, t1.w };
        #pragma unroll
        for (int i = 0; i < 8; ++i) {
            atomicAdd(&lsum[c0 + i], v[i]);
            atomicAdd(&lsq[c0 + i], v[i] * v[i]);
        }
    }
    __syncthreads();
    if (tid < 32) {
        part[(size_t)blockIdx.x * 64 + tid] = lsum[tid];
        part[(size_t)blockIdx.x * 64 + 32 + tid] = lsq[tid];
    }
}

// ---------------- reduce stats partials [nblk][64] + compute BN scale/shift
__global__ __launch_bounds__(1024)
void k_statsr(const float* __restrict__ part, int nblk,
              const float* __restrict__ g, const float* __restrict__ bb,
              float* __restrict__ sc, float* __restrict__ sh, float invN)
{
    __shared__ float l[1024];
    int tid = threadIdx.x;
    int col = tid & 63, grp = tid >> 6;
    float a = 0.f;
    #pragma unroll 8
    for (int j = grp; j < nblk; j += 16) a += part[(size_t)j * 64 + col];
    l[tid] = a;
    __syncthreads();
    if (tid < 64) {
        float s = 0.f;
        #pragma unroll
        for (int gq = 0; gq < 16; ++gq) s += l[gq * 64 + tid];
        l[tid] = s;
    }
    __syncthreads();
    if (tid < 32) {
        float m = l[tid] * invN;
        float v = l[32 + tid] * invN - m * m;
        float s = g[tid] * rsqrtf(v + 1e-4f);
        sc[tid] = s;
        sh[tid] = bb[tid] - m * s;
    }
}

// ---------------- f32 -> bf16 copy (4 thr/voxel)
__global__ __launch_bounds__(256)
void k_cvt(const float* __restrict__ t, ushort* __restrict__ out, int N)
{
    int gid = blockIdx.x * 256 + threadIdx.x;
    int n = gid >> 2;
    if (n >= N) return;
    int c0 = (gid & 3) * 8;
    const float* tr = t + (size_t)n * 32 + c0;
    float4 t0 = *(const float4*)tr, t1 = *(const float4*)(tr + 4);
    uint4 o; o.x = pk2(t0.x, t0.y); o.y = pk2(t0.z, t0.w);
    o.z = pk2(t1.x, t1.y); o.w = pk2(t1.z, t1.w);
    *(uint4*)(out + (size_t)n * 32 + c0) = o;
}

// ---------------- a_b = bf16(relu(t*sc+sh)) (4 thr/voxel)
__global__ __launch_bounds__(256)
void k_bnact(const float* __restrict__ t, const float* __restrict__ sc,
             const float* __restrict__ sh, ushort* __restrict__ out, int N)
{
    int gid = blockIdx.x * 256 + threadIdx.x;
    int n = gid >> 2;
    if (n >= N) return;
    int c0 = (gid & 3) * 8;
    const float* tr = t + (size_t)n * 32 + c0;
    float4 t0 = *(const float4*)tr, t1 = *(const float4*)(tr + 4);
    float g0 = fmaxf(t0.x * sc[c0+0] + sh[c0+0], 0.f);
    float g1 = fmaxf(t0.y * sc[c0+1] + sh[c0+1], 0.f);
    float g2 = fmaxf(t0.z * sc[c0+2] + sh[c0+2], 0.f);
    float g3 = fmaxf(t0.w * sc[c0+3] + sh[c0+3], 0.f);
    float g4 = fmaxf(t1.x * sc[c0+4] + sh[c0+4], 0.f);
    float g5 = fmaxf(t1.y * sc[c0+5] + sh[c0+5], 0.f);
    float g6 = fmaxf(t1.z * sc[c0+6] + sh[c0+6], 0.f);
    float g7 = fmaxf(t1.w * sc[c0+7] + sh[c0+7], 0.f);
    uint4 o; o.x = pk2(g0, g1); o.y = pk2(g2, g3); o.z = pk2(g4, g5); o.w = pk2(g6, g7);
    *(uint4*)(out + (size_t)n * 32 + c0) = o;
}

// ---------------- h1 = relu(bn(t)+h) IN-PLACE on hr; per-block (b,c) sum/max partials
__global__ __launch_bounds__(256)
void k_comb1(const float* __restrict__ t, const float* __restrict__ sc,
             const float* __restrict__ sh, const int* __restrict__ bids,
             float* hr, float* __restrict__ part, int N)
{
    __shared__ float lsum[BMAX * 32];
    __shared__ int   lmax[BMAX * 32];
    int tid = threadIdx.x;
    if (tid < BMAX * 32) { lsum[tid] = 0.f; lmax[tid] = 0; }
    __syncthreads();
    int gid = blockIdx.x * 256 + tid;
    int n = gid >> 2;
    int c0 = (gid & 3) * 8;
    if (n < N) {
        int b = bids[n];
        const float* tr = t + (size_t)n * 32 + c0;
        float* rr = hr + (size_t)n * 32 + c0;
        float4 t0 = *(const float4*)tr, t1 = *(const float4*)(tr + 4);
        float4 r0 = *(const float4*)rr, r1 = *(const float4*)(rr + 4);
        float v[8];
        v[0] = fmaxf(t0.x * sc[c0+0] + sh[c0+0] + r0.x, 0.f);
        v[1] = fmaxf(t0.y * sc[c0+1] + sh[c0+1] + r0.y, 0.f);
        v[2] = fmaxf(t0.z * sc[c0+2] + sh[c0+2] + r0.z, 0.f);
        v[3] = fmaxf(t0.w * sc[c0+3] + sh[c0+3] + r0.w, 0.f);
        v[4] = fmaxf(t1.x * sc[c0+4] + sh[c0+4] + r1.x, 0.f);
        v[5] = fmaxf(t1.y * sc[c0+5] + sh[c0+5] + r1.y, 0.f);
        v[6] = fmaxf(t1.z * sc[c0+6] + sh[c0+6] + r1.z, 0.f);
        v[7] = fmaxf(t1.w * sc[c0+7] + sh[c0+7] + r1.w, 0.f);
        float4 o0 = { v[0], v[1], v[2], v[3] };
        float4 o1 = { v[4], v[5], v[6], v[7] };
        *(float4*)rr = o0;
        *(float4*)(rr + 4) = o1;
        int base = b * 32 + c0;
        #pragma unroll
        for (int i = 0; i < 8; ++i) {
            atomicAdd(&lsum[base + i], v[i]);
            atomicMax(&lmax[base + i], __float_as_int(v[i]));
        }
    }
    __syncthreads();
    if (tid < 128) part[(size_t)blockIdx.x * 256 + tid] = lsum[tid];
    else           part[(size_t)blockIdx.x * 256 + tid] = __int_as_float(lmax[tid - 128]);
}

// ---------------- stage 1 reduce of comb1 partials: [nblk][256] -> [64][256]
__global__ __launch_bounds__(256)
void k_attred(const float* __restrict__ part, int nblk, float* __restrict__ out)
{
    int tid = threadIdx.x;
    int blk = blockIdx.x;
    if (tid < 128) {
        float a = 0.f;
        #pragma unroll 4
        for (int j = blk; j < nblk; j += 64) a += part[(size_t)j * 256 + tid];
        out[(size_t)blk * 256 + tid] = a;
    } else {
        float m = 0.f;
        #pragma unroll 4
        for (int j = blk; j < nblk; j += 64) m = fmaxf(m, part[(size_t)j * 256 + tid]);
        out[(size_t)blk * 256 + tid] = m;
    }
}

// ---------------- channel attention
__global__ void k_att(const float* __restrict__ part2, const float* __restrict__ cnt,
                      const float* __restrict__ ca1, const float* __restrict__ ca2,
                      float* __restrict__ att)
{
    __shared__ float seg[256];
    int tid = threadIdx.x;
    if (tid < 128) {
        float a = 0.f;
        #pragma unroll 8
        for (int j = 0; j < 64; ++j) a += part2[j * 256 + tid];
        seg[tid] = a;
    } else {
        float m = 0.f;
        #pragma unroll 8
        for (int j = 0; j < 64; ++j) m = fmaxf(m, part2[j * 256 + tid]);
        seg[tid] = m;
    }
    __syncthreads();
    int b = tid >> 6;
    int lane = tid & 63;
    bool actc = lane < 32;
    int c = lane & 31;
    float avg = actc ? seg[b * 32 + c] / cnt[b] : 0.f;
    float mx  = actc ? seg[128 + b * 32 + c] : 0.f;
    float h[8];
    #pragma unroll
    for (int i = 0; i < 4; ++i) {
        float w = actc ? ca1[c * 4 + i] : 0.f;
        h[i] = avg * w;
        h[i + 4] = mx * w;
    }
    #pragma unroll
    for (int off = 32; off; off >>= 1) {
        #pragma unroll
        for (int i = 0; i < 8; ++i) h[i] += __shfl_xor(h[i], off, 64);
    }
    if (actc) {
        float o = 0.f;
        #pragma unroll
        for (int i = 0; i < 4; ++i)
            o += (fmaxf(h[i], 0.f) + fmaxf(h[i + 4], 0.f)) * ca2[i * 32 + c];
        att[b * 32 + c] = sigmoidf_(o);
    }
}

// ---------------- hatt = h1*att[b] (4 thr/voxel); f32 + bf16 mirror
__global__ __launch_bounds__(256)
void k_scale_cvt(const float* __restrict__ h1, const float* __restrict__ att,
                 const int* __restrict__ bids, float* __restrict__ hatt,
                 ushort* __restrict__ hattb, int N)
{
    int gid = blockIdx.x * 256 + threadIdx.x;
    int n = gid >> 2;
    if (n >= N) return;
    int c0 = (gid & 3) * 8;
    const float* hrp = h1 + (size_t)n * 32 + c0;
    const float* ar = att + bids[n] * 32 + c0;
    float4 h0 = *(const float4*)hrp, h1v = *(const float4*)(hrp + 4);
    float4 a0 = *(const float4*)ar, a1 = *(const float4*)(ar + 4);
    float g0 = h0.x * a0.x, g1 = h0.y * a0.y, g2 = h0.z * a0.z, g3 = h0.w * a0.w;
    float g4 = h1v.x * a1.x, g5 = h1v.y * a1.y, g6 = h1v.z * a1.z, g7 = h1v.w * a1.w;
    float4 w0 = { g0, g1, g2, g3 };
    float4 w1 = { g4, g5, g6, g7 };
    *(float4*)(hatt + (size_t)n * 32 + c0) = w0;
    *(float4*)(hatt + (size_t)n * 32 + c0 + 4) = w1;
    uint4 o; o.x = pk2(g0, g1); o.y = pk2(g2, g3); o.z = pk2(g4, g5); o.w = pk2(g6, g7);
    *(uint4*)(hattb + (size_t)n * 32 + c0) = o;
}

// ---------------- h2 = relu(bn(t)+hres) IN-PLACE on hr; partial sums for final BN
__global__ __launch_bounds__(256)
void k_comb2(const float* __restrict__ t, const float* __restrict__ sc,
             const float* __restrict__ sh, float* hr, float* __restrict__ part, int N)
{
    __shared__ float lsum[32];
    __shared__ float lsq[32];
    int tid = threadIdx.x;
    if (tid < 32) { lsum[tid] = 0.f; lsq[tid] = 0.f; }
    __syncthreads();
    int gid = blockIdx.x * 256 + tid;
    int n = gid >> 2;
    int c0 = (gid & 3) * 8;
    if (n < N) {
        const float* tr = t + (size_t)n * 32 + c0;
        float* rr = hr + (size_t)n * 32 + c0;
        float4 t0 = *(const float4*)tr, t1 = *(const float4*)(tr + 4);
        float4 h0 = *(const float4*)rr, h1 = *(const float4*)(rr + 4);
        float v[8];
        v[0] = fmaxf(t0.x * sc[c0+0] + sh[c0+0] + h0.x, 0.f);
        v[1] = fmaxf(t0.y * sc[c0+1] + sh[c0+1] + h0.y, 0.f);
        v[2] = fmaxf(t0.z * sc[c0+2] + sh[c0+2] + h0.z, 0.f);
        v[3] = fmaxf(t0.w * sc[c0+3] + sh[c0+3] + h0.w, 0.f);
        v[4] = fmaxf(t1.x * sc[c0+4] + sh[c0+4] + h1.x, 0.f);
        v[5] = fmaxf(t1.y * sc[c0+5] + sh[c0+5] + h1.y, 0.f);
        v[6] = fmaxf(t1.z * sc[c0+6] + sh[c0+6] + h1.z, 0.f);
        v[7] = fmaxf(t1.w * sc[c0+7] + sh[c0+7] + h1.w, 0.f);
        float4 o0 = { v[0], v[1], v[2], v[3] };
        float4 o1 = { v[4], v[5], v[6], v[7] };
        *(float4*)rr = o0;
        *(float4*)(rr + 4) = o1;
        #pragma unroll
        for (int i = 0; i < 8; ++i) {
            atomicAdd(&lsum[c0 + i], v[i]);
            atomicAdd(&lsq[c0 + i], v[i] * v[i]);
        }
    }
    __syncthreads();
    if (tid < 32) {
        part[(size_t)blockIdx.x * 64 + tid] = lsum[tid];
        part[(size_t)blockIdx.x * 64 + 32 + tid] = lsq[tid];
    }
}

// ---------------- out = relu(bn5(h2)) @ lin_w + lin_b
__global__ __launch_bounds__(256)
void k_final(const float* __restrict__ h2, const float* __restrict__ sc,
             const float* __restrict__ sh, const float* __restrict__ lw,
             const float* __restrict__ lb, float* __restrict__ out, int N)
{
    int n = blockIdx.x * 256 + threadIdx.x;
    if (n >= N) return;
    const float* hr = h2 + (size_t)n * 32;
    float acc[26];
    #pragma unroll
    for (int o = 0; o < 26; ++o) acc[o] = lb[o];
    #pragma unroll
    for (int c4 = 0; c4 < 32; c4 += 4) {
        float4 hv = *(const float4*)(hr + c4);
        float xs[4] = { hv.x, hv.y, hv.z, hv.w };
        #pragma unroll
        for (int cc = 0; cc < 4; ++cc) {
            int c = c4 + cc;
            float x = fmaxf(xs[cc] * sc[c] + sh[c], 0.f);
            const float* wr = lw + c * 26;
            #pragma unroll
            for (int o = 0; o < 26; ++o) acc[o] += x * wr[o];
        }
    }
    float* orow = out + (size_t)n * 26;
    #pragma unroll
    for (int o = 0; o < 26; ++o) orow[o] = acc[o];
}

extern "C" void kernel_launch(void* const* d_in, const int* in_sizes, int n_in,
                              void* d_out, int out_size, void* d_ws, size_t ws_size,
                              hipStream_t stream)
{
    const float* feat_sem = (const float*)d_in[0];
    const float* feat_mos = (const float*)d_in[1];
    const float* fus_sp_w = (const float*)d_in[2];
    const float* fus_sp_b = (const float*)d_in[3];
    const float* fus_ch_w = (const float*)d_in[4];
    const float* fus_ch_b = (const float*)d_in[5];
    const float* conv_w   = (const float*)d_in[6];
    const float* conv_b   = (const float*)d_in[7];
    const float* r1c1_w   = (const float*)d_in[8];
    const float* r1g1     = (const float*)d_in[9];
    const float* r1b1     = (const float*)d_in[10];
    const float* r1c2_w   = (const float*)d_in[11];
    const float* r1g2     = (const float*)d_in[12];
    const float* r1b2     = (const float*)d_in[13];
    const float* ca1_w    = (const float*)d_in[14];
    const float* ca2_w    = (const float*)d_in[15];
    const float* r2c1_w   = (const float*)d_in[16];
    const float* r2g1     = (const float*)d_in[17];
    const float* r2b1     = (const float*)d_in[18];
    const float* r2c2_w   = (const float*)d_in[19];
    const float* r2g2     = (const float*)d_in[20];
    const float* r2b2     = (const float*)d_in[21];
    const float* out_g    = (const float*)d_in[22];
    const float* out_b    = (const float*)d_in[23];
    const float* lin_w    = (const float*)d_in[24];
    const float* lin_b    = (const float*)d_in[25];
    const int*   bids     = (const int*)d_in[26];
    const int*   nbr      = (const int*)d_in[27];
    int N = in_sizes[0] / 64;

    float* ws = (float*)d_ws;
    float* S1 = ws;                                   // 32N f32
    float* S2 = ws + (size_t)32 * N;                  // 32N f32
    float* S3 = ws + (size_t)64 * N;                  // 32N f32 (+pad)
    ushort* BB1 = (ushort*)(ws + (size_t)96 * N + 32);    // 32*(N+16) ushorts
    ushort* BB2 = BB1 + (size_t)32 * (N + 16);
    float* sbuf = S2;                                 // alias: dead before r1c1 writes S2
    ushort* FGB = (ushort*)S3;                        // alias: dead before r1c2 writes S3
    float* segpart = S1;                              // alias: dead before conv0 writes S1
    float* st = ws + (size_t)128 * N + 1024;
    float* seg_fm = st;                   // 256
    float* cnt    = st + 256;             // 4
    float* vec    = st + 260;             // 256
    float* bnsc   = st + 516;             // 5*32
    float* bnsh   = st + 676;             // 5*32
    float* attbuf = st + 840;             // 128
    int*   gcnt   = (int*)(st + 980);     // 27 ints
    float* pcnt   = st + 1024;            // up to 2048
    float* ppbuf  = st + 4096;            // ((4N+255)/256)*64
    float* partbuf= ppbuf + ((size_t)(N + 63) / 64) * 64 + 64;   // ((4N+255)/256)*256
    float* at2    = partbuf + ((size_t)4 * N + 255) / 256 * 256 + 256; // 64*256
    ushort* wpk0  = (ushort*)(at2 + 16384);  // 55296 + 4*27648 = 165888 ushorts
    ushort* wpk1 = wpk0 + 55296;
    ushort* wpk2 = wpk1 + 27648;
    ushort* wpk3 = wpk2 + 27648;
    ushort* wpk4 = wpk3 + 27648;
    int2* pairs = (int2*)(wpk0 + 165888);    // 27*CAP int2 = 3.5 MB

    int nb   = (N + 255) / 256;
    int nb4  = (4 * N + 255) / 256;
    int nb8  = (8 * N + 255) / 256;
    int nw64 = (N + 63) / 64;
    const int NSC = 27 * 256;     // scatter blocks: 27 taps x 1024 tiles / 4 waves
    const int NSEG = 512;
    float invN = 1.f / (float)N;

    hipMemsetAsync(gcnt, 0, 27 * sizeof(int), stream);
    k_wpack_all<<<81, 256, 0, stream>>>(conv_w, r1c1_w, r1c2_w, r2c1_w, r2c2_w, wpk0);
    k_rule<<<nw64, 256, 0, stream>>>(nbr, pairs, gcnt, N);

    k_fuse_s<<<nb, 256, 0, stream>>>(feat_mos, fus_sp_w, fus_sp_b, bids, sbuf, pcnt, N);
    k_seg_part<<<NSEG, 256, 0, stream>>>(feat_sem, sbuf, bids, segpart, N);
    k_seg_red<<<1, 1024, 0, stream>>>(segpart, seg_fm, NSEG);
    k_vec<<<1, 256, 0, stream>>>(seg_fm, pcnt, nb, fus_ch_w, fus_ch_b, vec, cnt);
    k_gate_cvt<<<nb8, 256, 0, stream>>>(feat_sem, sbuf, vec, bids, FGB, N);

    // conv0: 64->32 with bias
    k_center<64, true><<<nb4, 256, 0, stream>>>(FGB, wpk0 + 13 * 2048, conv_b, S1, N);
    k_scatter<64><<<NSC, 256, 0, stream>>>(FGB, pairs, gcnt, wpk0, S1, N);
    k_cvt<<<nb4, 256, 0, stream>>>(S1, BB1, N);

    // r1c1
    k_center<32, false><<<nb4, 256, 0, stream>>>(BB1, wpk1 + 13 * 1024, nullptr, S2, N);
    k_scatter<32><<<NSC, 256, 0, stream>>>(BB1, pairs, gcnt, wpk1, S2, N);
    k_statsp<<<nb4, 256, 0, stream>>>(S2, ppbuf, N);
    k_statsr<<<1, 1024, 0, stream>>>(ppbuf, nb4, r1g1, r1b1, bnsc + 0, bnsh + 0, invN);
    k_bnact<<<nb4, 256, 0, stream>>>(S2, bnsc + 0, bnsh + 0, BB2, N);

    // r1c2
    k_center<32, false><<<nb4, 256, 0, stream>>>(BB2, wpk2 + 13 * 1024, nullptr, S3, N);
    k_scatter<32><<<NSC, 256, 0, stream>>>(BB2, pairs, gcnt, wpk2, S3, N);
    k_statsp<<<nb4, 256, 0, stream>>>(S3, ppbuf, N);
    k_statsr<<<1, 1024, 0, stream>>>(ppbuf, nb4, r1g2, r1b2, bnsc + 32, bnsh + 32, invN);

    k_comb1<<<nb4, 256, 0, stream>>>(S3, bnsc + 32, bnsh + 32, bids, S1, partbuf, N);
    k_attred<<<64, 256, 0, stream>>>(partbuf, nb4, at2);
    k_att<<<1, 256, 0, stream>>>(at2, cnt, ca1_w, ca2_w, attbuf);
    k_scale_cvt<<<nb4, 256, 0, stream>>>(S1, attbuf, bids, S2, BB1, N);

    // r2c1
    k_center<32, false><<<nb4, 256, 0, stream>>>(BB1, wpk3 + 13 * 1024, nullptr, S3, N);
    k_scatter<32><<<NSC, 256, 0, stream>>>(BB1, pairs, gcnt, wpk3, S3, N);
    k_statsp<<<nb4, 256, 0, stream>>>(S3, ppbuf, N);
    k_statsr<<<1, 1024, 0, stream>>>(ppbuf, nb4, r2g1, r2b1, bnsc + 64, bnsh + 64, invN);
    k_bnact<<<nb4, 256, 0, stream>>>(S3, bnsc + 64, bnsh + 64, BB2, N);

    // r2c2
    k_center<32, false><<<nb4, 256, 0, stream>>>(BB2, wpk4 + 13 * 1024, nullptr, S1, N);
    k_scatter<32><<<NSC, 256, 0, stream>>>(BB2, pairs, gcnt, wpk4, S1, N);
    k_statsp<<<nb4, 256, 0, stream>>>(S1, ppbuf, N);
    k_statsr<<<1, 1024, 0, stream>>>(ppbuf, nb4, r2g2, r2b2, bnsc + 96, bnsh + 96, invN);

    k_comb2<<<nb4, 256, 0, stream>>>(S1, bnsc + 96, bnsh + 96, S2, ppbuf, N);
    k_statsr<<<1, 1024, 0, stream>>>(ppbuf, nb4, out_g, out_b, bnsc + 128, bnsh + 128, invN);

    k_final<<<nb, 256, 0, stream>>>(S2, bnsc + 128, bnsh + 128, lin_w, lin_b, (float*)d_out, N);
}